// Round 1
// baseline (968.238 us; speedup 1.0000x reference)
//
#include <hip/hip_runtime.h>
#include <math.h>

#define BB 4
#define NN 4096
#define KK 32
#define HH 128
#define EE 8
#define NCHUNKS (KK / EE)

__device__ __forceinline__ float gelu_exact(float x) {
    return x * 0.5f * (1.0f + erff(x * 0.70710678118654752f));
}

// ---------------------------------------------------------------------------
// Kernel 1: per-node edge MLP + masked mean aggregation -> upd (B,N,H)
// Block = one node (b,n), 128 threads, thread j = output feature j.
// Self half of layer0 hoisted out of the per-edge loop (shared by all K edges).
// ---------------------------------------------------------------------------
__global__ __launch_bounds__(128) void edge_mlp_kernel(
    const float* __restrict__ enc, const float* __restrict__ mask,
    const float* __restrict__ dist, const int* __restrict__ eidx,
    const float* __restrict__ W0, const float* __restrict__ b0,
    const float* __restrict__ W1, const float* __restrict__ b1,
    const float* __restrict__ W2, const float* __restrict__ b2,
    float* __restrict__ upd)
{
    __shared__ float s_self[HH];
    __shared__ float s_src[HH][EE];   // transposed: [feature][edge]
    __shared__ float s_h0[HH][EE];
    __shared__ float s_h1[HH][EE];
    __shared__ int   s_idx[KK];
    __shared__ float s_dist[KK];

    const int bn = blockIdx.x;        // b*N + n
    const int b  = bn >> 12;          // N = 4096
    const int j  = threadIdx.x;       // feature 0..127

    const float mask_n   = mask[bn];
    const float self_raw = enc[(size_t)bn * HH + j];
    s_self[j] = self_raw * mask_n;
    if (j < KK) {
        s_idx[j]  = eidx[(size_t)bn * KK + j];
        s_dist[j] = dist[(size_t)bn * KK + j];
    }
    __syncthreads();

    int vcnt = 0;
    #pragma unroll
    for (int k = 0; k < KK; ++k) vcnt += (s_idx[k] >= 0) ? 1 : 0;
    const float inv_vcnt = 1.0f / (float)(vcnt < 1 ? 1 : vcnt);

    // layer0 self-feature part (rows 128..255 of W0) + bias, once per node
    float selfacc = b0[j];
    #pragma unroll 4
    for (int i = 0; i < HH; ++i)
        selfacc = fmaf(s_self[i], W0[(size_t)(HH + i) * HH + j], selfacc);
    const float w_dist = W0[(size_t)256 * HH + j];
    const float bias1  = b1[j];
    const float bias2  = b2[j];

    const float* __restrict__ encb  = enc  + (size_t)b * NN * HH;
    const float* __restrict__ maskb = mask + (size_t)b * NN;

    float msum = 0.0f;

    for (int c = 0; c < NCHUNKS; ++c) {
        // gather: feature j of 8 neighbor rows (coalesced across lanes)
        #pragma unroll
        for (int e = 0; e < EE; ++e) {
            int id = s_idx[c * EE + e];
            int ci = id < 0 ? 0 : id;
            s_src[j][e] = encb[(size_t)ci * HH + j] * maskb[ci];
        }
        __syncthreads();

        float acc[EE];
        #pragma unroll
        for (int e = 0; e < EE; ++e)
            acc[e] = fmaf(s_dist[c * EE + e], w_dist, selfacc);
        #pragma unroll 4
        for (int i = 0; i < HH; ++i) {
            float w = W0[(size_t)i * HH + j];
            #pragma unroll
            for (int e = 0; e < EE; ++e)
                acc[e] = fmaf(s_src[i][e], w, acc[e]);
        }
        #pragma unroll
        for (int e = 0; e < EE; ++e) s_h0[j][e] = gelu_exact(acc[e]);
        __syncthreads();

        #pragma unroll
        for (int e = 0; e < EE; ++e) acc[e] = bias1;
        #pragma unroll 4
        for (int i = 0; i < HH; ++i) {
            float w = W1[(size_t)i * HH + j];
            #pragma unroll
            for (int e = 0; e < EE; ++e)
                acc[e] = fmaf(s_h0[i][e], w, acc[e]);
        }
        #pragma unroll
        for (int e = 0; e < EE; ++e) s_h1[j][e] = gelu_exact(acc[e]);
        __syncthreads();

        #pragma unroll
        for (int e = 0; e < EE; ++e) acc[e] = bias2;
        #pragma unroll 4
        for (int i = 0; i < HH; ++i) {
            float w = W2[(size_t)i * HH + j];
            #pragma unroll
            for (int e = 0; e < EE; ++e)
                acc[e] = fmaf(s_h1[i][e], w, acc[e]);
        }
        #pragma unroll
        for (int e = 0; e < EE; ++e) {
            if (s_idx[c * EE + e] >= 0) msum += gelu_exact(acc[e]);
        }
        __syncthreads();
    }

    upd[(size_t)bn * HH + j] = (self_raw + msum * inv_vcnt) * mask_n;
}

// ---------------------------------------------------------------------------
// Kernel 2a: partial sums/sumsq over 128-row chunks -> (B,32,H)
// ---------------------------------------------------------------------------
#define RCHUNK 128
__global__ __launch_bounds__(128) void reduce_partial_kernel(
    const float* __restrict__ upd, float* __restrict__ psum, float* __restrict__ psumsq)
{
    const int blk = blockIdx.x;        // B*32
    const int b = blk >> 5;
    const int p = blk & 31;
    const int j = threadIdx.x;
    const size_t base = ((size_t)b * NN + (size_t)p * RCHUNK) * HH + j;
    float s = 0.f, s2 = 0.f;
    #pragma unroll 4
    for (int r = 0; r < RCHUNK; ++r) {
        float v = upd[base + (size_t)r * HH];
        s += v;
        s2 = fmaf(v, v, s2);
    }
    psum[(size_t)blk * HH + j]   = s;
    psumsq[(size_t)blk * HH + j] = s2;
}

// ---------------------------------------------------------------------------
// Kernel 2b: combine partials -> mean, 1/std per (b, feature)
// var = (S2 - 2*mean*S1 + N*mean^2) / counts   (sum over ALL rows, /masked cnt)
// ---------------------------------------------------------------------------
__global__ __launch_bounds__(128) void finalize_stats_kernel(
    const float* __restrict__ psum, const float* __restrict__ psumsq,
    const float* __restrict__ mask, float* __restrict__ meanp, float* __restrict__ istdp)
{
    const int b = blockIdx.x;
    const int j = threadIdx.x;
    float s = 0.f, s2 = 0.f;
    #pragma unroll 4
    for (int c = 0; c < 32; ++c) {
        s  += psum[((size_t)b * 32 + c) * HH + j];
        s2 += psumsq[((size_t)b * 32 + c) * HH + j];
    }
    float cpart = 0.f;
    #pragma unroll 4
    for (int t = 0; t < NN / HH; ++t)
        cpart += mask[(size_t)b * NN + (size_t)t * HH + j];
    __shared__ float red[HH];
    red[j] = cpart;
    __syncthreads();
    for (int off = HH / 2; off > 0; off >>= 1) {
        if (j < off) red[j] += red[j + off];
        __syncthreads();
    }
    float counts = red[0];
    if (counts == 0.f) counts = 1.f;
    float mean = s / counts;
    float var  = (s2 - 2.f * mean * s + (float)NN * mean * mean) / counts;
    meanp[b * HH + j] = mean;
    istdp[b * HH + j] = 1.0f / sqrtf(var + 1e-5f);
}

// ---------------------------------------------------------------------------
// Kernel 3: normalize + write all 4 outputs (float32 throughout)
// ---------------------------------------------------------------------------
__global__ void write_out_kernel(
    const float* __restrict__ upd, const float* __restrict__ mask,
    const float* __restrict__ dist, const int* __restrict__ eidx,
    const float* __restrict__ meanp, const float* __restrict__ istdp,
    const float* __restrict__ scale, const float* __restrict__ shift,
    float* __restrict__ out)
{
    const size_t T0 = (size_t)BB * NN * HH;   // 2097152
    const size_t T1 = (size_t)BB * NN;        // 16384
    const size_t T2 = (size_t)BB * NN * KK;   // 524288
    const size_t stride = (size_t)gridDim.x * blockDim.x;
    const size_t t = (size_t)blockIdx.x * blockDim.x + threadIdx.x;

    for (size_t x = t; x < T0; x += stride) {
        int h = (int)(x & (HH - 1));
        size_t bn = x >> 7;
        int b = (int)(bn >> 12);
        float m = mask[bn];
        float v = (upd[x] - meanp[b * HH + h]) * istdp[b * HH + h] * scale[h] + shift[h];
        out[x] = v * m;
    }
    float* out1 = out + T0;
    for (size_t x = t; x < T1; x += stride) out1[x] = mask[x];
    float* out2 = out1 + T1;
    for (size_t x = t; x < T2; x += stride) out2[x] = dist[x];
    float* out3 = out2 + T2;
    for (size_t x = t; x < T2; x += stride) out3[x] = (float)eidx[x];
}

// ---------------------------------------------------------------------------
extern "C" void kernel_launch(void* const* d_in, const int* in_sizes, int n_in,
                              void* d_out, int out_size, void* d_ws, size_t ws_size,
                              hipStream_t stream) {
    const float* enc   = (const float*)d_in[0];
    const float* mask  = (const float*)d_in[1];
    const float* dist  = (const float*)d_in[2];
    const int*   eidx  = (const int*)  d_in[3];
    const float* W0    = (const float*)d_in[4];
    const float* b0    = (const float*)d_in[5];
    const float* W1    = (const float*)d_in[6];
    const float* b1    = (const float*)d_in[7];
    const float* W2    = (const float*)d_in[8];
    const float* b2    = (const float*)d_in[9];
    const float* scale = (const float*)d_in[10];
    const float* shift = (const float*)d_in[11];
    float* out = (float*)d_out;

    float* ws     = (float*)d_ws;
    float* upd    = ws;                               // B*N*H
    float* psum   = upd  + (size_t)BB * NN * HH;      // B*32*H
    float* psumsq = psum + (size_t)BB * 32 * HH;      // B*32*H
    float* meanp  = psumsq + (size_t)BB * 32 * HH;    // B*H
    float* istdp  = meanp  + (size_t)BB * HH;         // B*H

    edge_mlp_kernel<<<dim3(BB * NN), dim3(HH), 0, stream>>>(
        enc, mask, dist, eidx, W0, b0, W1, b1, W2, b2, upd);
    reduce_partial_kernel<<<dim3(BB * 32), dim3(HH), 0, stream>>>(upd, psum, psumsq);
    finalize_stats_kernel<<<dim3(BB), dim3(HH), 0, stream>>>(psum, psumsq, mask, meanp, istdp);
    write_out_kernel<<<dim3(1024), dim3(256), 0, stream>>>(
        upd, mask, dist, eidx, meanp, istdp, scale, shift, out);
}

// Round 2
// 328.344 us; speedup vs baseline: 2.9488x; 2.9488x over previous
//
#include <hip/hip_runtime.h>
#include <hip/hip_bf16.h>
#include <math.h>

#define BB 4
#define NN 4096
#define KK 32
#define HH 128

#define NPB 64        // nodes per block
#define THREADS 512   // 8 waves

typedef short bf16x8 __attribute__((ext_vector_type(8)));
typedef float f32x16 __attribute__((ext_vector_type(16)));
typedef unsigned int u32;

#define TBL_BYTES 32768
#define OFF_W0N 0
#define OFF_W1  TBL_BYTES
#define OFF_W2  (2*TBL_BYTES)
#define OFF_SELF (3*TBL_BYTES)                 // 64 nodes x 128 feat bf16 = 16384 B
#define OFF_IDX  (OFF_SELF + NPB*HH*2)         // 64*32*4 = 8192 B
#define OFF_DIST (OFF_IDX + NPB*KK*4)          // 8192 B
#define OFF_WD   (OFF_DIST + NPB*KK*4)         // 256 B
#define LDS_TOTAL (OFF_WD + HH*2)              // 131328 B

#define MFMA(a,b,c) __builtin_amdgcn_mfma_f32_32x32x16_bf16(a,b,c,0,0,0)

__device__ __forceinline__ u32 pack_bf2(float lo, float hi) {
    __hip_bfloat162 h = __float22bfloat162_rn(make_float2(lo, hi));
    u32 r; __builtin_memcpy(&r, &h, 4); return r;
}
__device__ __forceinline__ short f2bfs(float v) {
    __hip_bfloat16 h = __float2bfloat16(v);
    short r; __builtin_memcpy(&r, &h, 2); return r;
}
// tanh-form GELU: max abs err ~3e-4 vs exact erf form (well under tolerance)
__device__ __forceinline__ float gelu_t(float x) {
    float x2 = x * x;
    float t = x * fmaf(0.10294828f, x2, 2.30220913f);  // 2u*log2(e)
    float e = exp2f(t);
    float r = __builtin_amdgcn_rcpf(e + 1.0f);
    return fmaf(-x, r, x);                              // x * (1 - 1/(e+1))
}

union frag { bf16x8 v; u32 w[4]; };

// D(prev layer, [feat][edge]) -> fragments indexed [edge-row/col = lane&31][k = feats]
// Derivation vs verified C/D map (col=lane&31, row=(reg&3)+8*(reg>>2)+4*(lane>>5)):
//  slot(ks,r): pair-reg q = (r&1)+4*(ks&1)+2*hi_dest, src half = r>>1, mt_src = ks>>1.
#define TRANSITION(g, F) do {                                                   \
    u32 pk_[4][8];                                                              \
    _Pragma("unroll") for (int mt_=0; mt_<4; ++mt_)                             \
      _Pragma("unroll") for (int q_=0; q_<8; ++q_)                              \
        pk_[mt_][q_] = pack_bf2(g[mt_][2*q_], g[mt_][2*q_+1]);                  \
    _Pragma("unroll") for (int ks_=0; ks_<8; ++ks_)                             \
      _Pragma("unroll") for (int r_=0; r_<4; ++r_) {                            \
        const int q0_ = (r_&1) + 4*(ks_&1); const int mts_ = ks_>>1;            \
        u32 own_  = hi ? pk_[mts_][q0_+2] : pk_[mts_][q0_];                     \
        u32 give_ = hi ? pk_[mts_][q0_]   : pk_[mts_][q0_+2];                   \
        u32 got_  = (u32)__shfl_xor((int)give_, 32, 64);                        \
        F[ks_].w[r_] = ((r_>>1) == hi) ? own_ : got_;                           \
      }                                                                         \
} while (0)

// ---------------------------------------------------------------------------
// Kernel 0: encm = bf16(enc * mask)
// ---------------------------------------------------------------------------
__global__ __launch_bounds__(256) void encm_kernel(
    const float* __restrict__ enc, const float* __restrict__ mask,
    __hip_bfloat16* __restrict__ encm)
{
    size_t t = (size_t)blockIdx.x * 256 + threadIdx.x;
    size_t base = t * 8;
    if (base >= (size_t)BB * NN * HH) return;
    float m = mask[base >> 7];
    const float4* p = (const float4*)(enc + base);
    float4 a = p[0], c = p[1];
    uint4 o;
    o.x = pack_bf2(a.x * m, a.y * m);
    o.y = pack_bf2(a.z * m, a.w * m);
    o.z = pack_bf2(c.x * m, c.y * m);
    o.w = pack_bf2(c.z * m, c.w * m);
    *(uint4*)(encm + base) = o;
}

// ---------------------------------------------------------------------------
// Kernel 1: fused MFMA edge-MLP + masked mean -> upd (written into d_out[0:2M])
// ---------------------------------------------------------------------------
__global__ __launch_bounds__(THREADS, 2) void mpnn_kernel(
    const float* __restrict__ enc, const float* __restrict__ mask,
    const float* __restrict__ dist, const int* __restrict__ eidx,
    const __hip_bfloat16* __restrict__ encm,
    const float* __restrict__ W0, const float* __restrict__ b0,
    const float* __restrict__ W1, const float* __restrict__ b1,
    const float* __restrict__ W2, const float* __restrict__ b2,
    float* __restrict__ upd)
{
    extern __shared__ char lds[];
    const int tid  = threadIdx.x;
    const int wave = tid >> 6;
    const int lane = tid & 63;
    const int li   = lane & 31;
    const int hi   = lane >> 5;
    const int nodeBase = blockIdx.x * NPB;

    // ---- stage weight fragment tables (bf16, MFMA frag layout) ----
    // slot for elem (k, feat): frag(mt=feat>>5, ks=k>>4), lane = ((k>>3)&1)*32 + (feat&31), j = k&7
    for (int tbl = 0; tbl < 3; ++tbl) {
        const float* W = (tbl == 0) ? W0 : ((tbl == 1) ? W1 : W2);
        short* dst = (short*)(lds + tbl * TBL_BYTES);
        #pragma unroll
        for (int i = 0; i < (HH * HH) / THREADS; ++i) {
            int e = i * THREADS + tid;
            int feat = e & 127, k = e >> 7;
            float v = W[(size_t)k * HH + feat];
            int mt = feat >> 5, ks = k >> 4, h2 = (k >> 3) & 1, j = k & 7;
            dst[((mt * 8 + ks) * 64 + h2 * 32 + (feat & 31)) * 8 + j] = f2bfs(v);
        }
    }
    // meta: idx + dist
    int* sidx = (int*)(lds + OFF_IDX);
    float* sdist = (float*)(lds + OFF_DIST);
    for (int i = tid; i < NPB * KK; i += THREADS) {
        sidx[i]  = eidx[(size_t)nodeBase * KK + i];
        sdist[i] = dist[(size_t)nodeBase * KK + i];
    }
    short* swd = (short*)(lds + OFF_WD);
    if (tid < HH) swd[tid] = f2bfs(W0[(size_t)256 * HH + tid]);

    // ---- prologue: selfacc[node][feat] = b0 + self_enc . W0[128:256]  (bf16 in LDS) ----
    short* sself = (short*)(lds + OFF_SELF);
    {
        const int mt = wave & 3, nh = wave >> 2;
        const int lnode = nh * 32 + li;
        const int gnode = nodeBase + lnode;
        const int feat = mt * 32 + li;
        f32x16 acc;
        #pragma unroll
        for (int r = 0; r < 16; ++r) acc[r] = 0.f;
        #pragma unroll
        for (int ks = 0; ks < 8; ++ks) {
            bf16x8 afr;
            #pragma unroll
            for (int j = 0; j < 8; ++j) {
                int k = ks * 16 + hi * 8 + j;
                afr[j] = f2bfs(W0[(size_t)(HH + k) * HH + feat]);
            }
            bf16x8 bfr = *(const bf16x8*)(encm + (size_t)gnode * HH + ks * 16 + hi * 8);
            acc = MFMA(afr, bfr, acc);
        }
        #pragma unroll
        for (int q = 0; q < 8; ++q) {
            int r0 = 2 * q;
            int row0 = (r0 & 3) + 8 * (r0 >> 2) + 4 * hi;
            float v0 = acc[r0]     + b0[mt * 32 + row0];
            float v1 = acc[r0 + 1] + b0[mt * 32 + row0 + 1];
            *(u32*)((char*)sself + lnode * 256 + (mt * 32 + row0) * 2) = pack_bf2(v0, v1);
        }
    }
    __syncthreads();

    const int b = nodeBase >> 12;
    const __hip_bfloat16* encb = encm + (size_t)b * NN * HH;
    const bf16x8* w0t = (const bf16x8*)(lds + OFF_W0N);
    const bf16x8* w1t = (const bf16x8*)(lds + OFF_W1);
    const bf16x8* w2t = (const bf16x8*)(lds + OFF_W2);

    // constant bias fragments (extra-K rank-1 terms)
    bf16x8 A1x[4], B1x, A2x, B2x[4];
    {
        B1x = (bf16x8){}; A2x = (bf16x8){};
        if (!hi) { B1x[0] = (short)0x3F80; A2x[0] = (short)0x3F80; }
        #pragma unroll
        for (int mt = 0; mt < 4; ++mt) {
            short sb1 = f2bfs(b1[mt * 32 + li]);
            short sb2 = f2bfs(b2[mt * 32 + li]);
            A1x[mt] = (bf16x8){}; B2x[mt] = (bf16x8){};
            if (!hi) { A1x[mt][0] = sb1; B2x[mt][0] = sb2; }
        }
    }

    #pragma unroll 1
    for (int i = 0; i < NPB / 8; ++i) {
        const int node_local = wave * (NPB / 8) + i;
        const int gnode = nodeBase + node_local;

        int ie = sidx[node_local * KK + li];
        bool valid = ie >= 0;
        int ic = valid ? ie : 0;
        u32 vmask = (u32)__ballot(valid);
        int vc = __popc(vmask);
        float inv_vc = 1.0f / (float)(vc < 1 ? 1 : vc);
        float dste = sdist[node_local * KK + li];
        float mask_n = mask[gnode];

        // gather neighbor rows (bf16, premasked)
        const char* gbase = (const char*)(encb + (size_t)ic * HH) + hi * 16;
        bf16x8 B0[8];
        #pragma unroll
        for (int ks = 0; ks < 8; ++ks) B0[ks] = *(const bf16x8*)(gbase + ks * 32);

        // per-node extra-K frags: j0: wd*dist, j1: selfacc*1
        bf16x8 A0x[4], B0x;
        #pragma unroll
        for (int mt = 0; mt < 4; ++mt) {
            short w_ = swd[mt * 32 + li];
            short s_ = sself[node_local * HH + mt * 32 + li];
            A0x[mt] = (bf16x8){};
            if (!hi) { A0x[mt][0] = w_; A0x[mt][1] = s_; }
        }
        B0x = (bf16x8){};
        if (!hi) { B0x[0] = f2bfs(dste); B0x[1] = (short)0x3F80; }

        // ---- layer 0 (transposed): D0[feat][edge] ----
        f32x16 acc0[4];
        #pragma unroll
        for (int mt = 0; mt < 4; ++mt)
            #pragma unroll
            for (int r = 0; r < 16; ++r) acc0[mt][r] = 0.f;
        #pragma unroll
        for (int ks = 0; ks < 8; ++ks)
            #pragma unroll
            for (int mt = 0; mt < 4; ++mt)
                acc0[mt] = MFMA(w0t[(mt * 8 + ks) * 64 + lane], B0[ks], acc0[mt]);
        #pragma unroll
        for (int mt = 0; mt < 4; ++mt) acc0[mt] = MFMA(A0x[mt], B0x, acc0[mt]);

        #pragma unroll
        for (int mt = 0; mt < 4; ++mt)
            #pragma unroll
            for (int r = 0; r < 16; ++r) acc0[mt][r] = gelu_t(acc0[mt][r]);

        frag F1[8];
        TRANSITION(acc0, F1);

        // ---- layer 1 (transposed) ----
        f32x16 acc1[4];
        #pragma unroll
        for (int mt = 0; mt < 4; ++mt)
            #pragma unroll
            for (int r = 0; r < 16; ++r) acc1[mt][r] = 0.f;
        #pragma unroll
        for (int ks = 0; ks < 8; ++ks)
            #pragma unroll
            for (int mt = 0; mt < 4; ++mt)
                acc1[mt] = MFMA(w1t[(mt * 8 + ks) * 64 + lane], F1[ks].v, acc1[mt]);
        #pragma unroll
        for (int mt = 0; mt < 4; ++mt) acc1[mt] = MFMA(A1x[mt], B1x, acc1[mt]);

        #pragma unroll
        for (int mt = 0; mt < 4; ++mt)
            #pragma unroll
            for (int r = 0; r < 16; ++r) acc1[mt][r] = gelu_t(acc1[mt][r]);

        frag F2[8];
        TRANSITION(acc1, F2);

        // ---- layer 2 (normal): D2[edge][feat] ----
        f32x16 acc2[4];
        #pragma unroll
        for (int nt = 0; nt < 4; ++nt)
            #pragma unroll
            for (int r = 0; r < 16; ++r) acc2[nt][r] = 0.f;
        #pragma unroll
        for (int ks = 0; ks < 8; ++ks)
            #pragma unroll
            for (int nt = 0; nt < 4; ++nt)
                acc2[nt] = MFMA(F2[ks].v, w2t[(nt * 8 + ks) * 64 + lane], acc2[nt]);
        #pragma unroll
        for (int nt = 0; nt < 4; ++nt) acc2[nt] = MFMA(A2x, B2x[nt], acc2[nt]);

        // ---- epilogue: gelu, valid-mask, sum over 32 edges ----
        float s[4];
        #pragma unroll
        for (int nt = 0; nt < 4; ++nt) {
            float t = 0.f;
            #pragma unroll
            for (int r = 0; r < 16; ++r) {
                float v = gelu_t(acc2[nt][r]);
                int edge = (r & 3) + 8 * (r >> 2) + 4 * hi;
                t += ((vmask >> edge) & 1) ? v : 0.f;
            }
            t += __shfl_xor(t, 32, 64);
            s[nt] = t;
        }
        #pragma unroll
        for (int k2 = 0; k2 < 2; ++k2) {
            int nt = hi * 2 + k2;
            int f = nt * 32 + li;
            float u = (enc[(size_t)gnode * HH + f] + s[nt] * inv_vc) * mask_n;
            upd[(size_t)gnode * HH + f] = u;
        }
    }
}

// ---------------------------------------------------------------------------
// Kernel 2a: partial sums/sumsq over 128-row chunks -> (B,32,H)
// ---------------------------------------------------------------------------
#define RCHUNK 128
__global__ __launch_bounds__(128) void reduce_partial_kernel(
    const float* __restrict__ upd, float* __restrict__ psum, float* __restrict__ psumsq)
{
    const int blk = blockIdx.x;
    const int b = blk >> 5;
    const int p = blk & 31;
    const int j = threadIdx.x;
    const size_t base = ((size_t)b * NN + (size_t)p * RCHUNK) * HH + j;
    float s = 0.f, s2 = 0.f;
    #pragma unroll 4
    for (int r = 0; r < RCHUNK; ++r) {
        float v = upd[base + (size_t)r * HH];
        s += v;
        s2 = fmaf(v, v, s2);
    }
    psum[(size_t)blk * HH + j]   = s;
    psumsq[(size_t)blk * HH + j] = s2;
}

// ---------------------------------------------------------------------------
// Kernel 2b: combine partials -> mean, 1/std per (b, feature)
// ---------------------------------------------------------------------------
__global__ __launch_bounds__(128) void finalize_stats_kernel(
    const float* __restrict__ psum, const float* __restrict__ psumsq,
    const float* __restrict__ mask, float* __restrict__ meanp, float* __restrict__ istdp)
{
    const int b = blockIdx.x;
    const int j = threadIdx.x;
    float s = 0.f, s2 = 0.f;
    #pragma unroll 4
    for (int c = 0; c < 32; ++c) {
        s  += psum[((size_t)b * 32 + c) * HH + j];
        s2 += psumsq[((size_t)b * 32 + c) * HH + j];
    }
    float cpart = 0.f;
    #pragma unroll 4
    for (int t = 0; t < NN / HH; ++t)
        cpart += mask[(size_t)b * NN + (size_t)t * HH + j];
    __shared__ float red[HH];
    red[j] = cpart;
    __syncthreads();
    for (int off = HH / 2; off > 0; off >>= 1) {
        if (j < off) red[j] += red[j + off];
        __syncthreads();
    }
    float counts = red[0];
    if (counts == 0.f) counts = 1.f;
    float mean = s / counts;
    float var  = (s2 - 2.f * mean * s + (float)NN * mean * mean) / counts;
    meanp[b * HH + j] = mean;
    istdp[b * HH + j] = 1.0f / sqrtf(var + 1e-5f);
}

// ---------------------------------------------------------------------------
// Kernel 3: normalize out0 in place + write pass-through outputs
// ---------------------------------------------------------------------------
__global__ void write_out_kernel(
    const float* __restrict__ mask, const float* __restrict__ dist,
    const int* __restrict__ eidx, const float* __restrict__ meanp,
    const float* __restrict__ istdp, const float* __restrict__ scale,
    const float* __restrict__ shift, float* __restrict__ out)
{
    const size_t T0 = (size_t)BB * NN * HH;
    const size_t T1 = (size_t)BB * NN;
    const size_t T2 = (size_t)BB * NN * KK;
    const size_t stride = (size_t)gridDim.x * blockDim.x;
    const size_t t = (size_t)blockIdx.x * blockDim.x + threadIdx.x;

    for (size_t x = t; x < T0; x += stride) {
        int h = (int)(x & (HH - 1));
        size_t bn = x >> 7;
        int b = (int)(bn >> 12);
        float m = mask[bn];
        float v = (out[x] - meanp[b * HH + h]) * istdp[b * HH + h] * scale[h] + shift[h];
        out[x] = v * m;
    }
    float* out1 = out + T0;
    for (size_t x = t; x < T1; x += stride) out1[x] = mask[x];
    float* out2 = out1 + T1;
    for (size_t x = t; x < T2; x += stride) out2[x] = dist[x];
    float* out3 = out2 + T2;
    for (size_t x = t; x < T2; x += stride) out3[x] = (float)eidx[x];
}

// ---------------------------------------------------------------------------
extern "C" void kernel_launch(void* const* d_in, const int* in_sizes, int n_in,
                              void* d_out, int out_size, void* d_ws, size_t ws_size,
                              hipStream_t stream) {
    const float* enc   = (const float*)d_in[0];
    const float* mask  = (const float*)d_in[1];
    const float* dist  = (const float*)d_in[2];
    const int*   eidx  = (const int*)  d_in[3];
    const float* W0    = (const float*)d_in[4];
    const float* b0    = (const float*)d_in[5];
    const float* W1    = (const float*)d_in[6];
    const float* b1    = (const float*)d_in[7];
    const float* W2    = (const float*)d_in[8];
    const float* b2    = (const float*)d_in[9];
    const float* scale = (const float*)d_in[10];
    const float* shift = (const float*)d_in[11];
    float* out = (float*)d_out;
    float* upd = out;   // pre-norm upd lives in out[0:B*N*H], normalized in place later

    __hip_bfloat16* encm = (__hip_bfloat16*)d_ws;
    char* wsc = (char*)d_ws + (size_t)BB * NN * HH * 2;
    float* psum   = (float*)wsc;
    float* psumsq = psum + (size_t)BB * 32 * HH;
    float* meanp  = psumsq + (size_t)BB * 32 * HH;
    float* istdp  = meanp + (size_t)BB * HH;

    hipFuncSetAttribute((const void*)mpnn_kernel,
                        hipFuncAttributeMaxDynamicSharedMemorySize, LDS_TOTAL);

    encm_kernel<<<dim3((BB * NN * HH / 8 + 255) / 256), dim3(256), 0, stream>>>(enc, mask, encm);
    mpnn_kernel<<<dim3((BB * NN) / NPB), dim3(THREADS), LDS_TOTAL, stream>>>(
        enc, mask, dist, eidx, encm, W0, b0, W1, b1, W2, b2, upd);
    reduce_partial_kernel<<<dim3(BB * 32), dim3(128), 0, stream>>>(upd, psum, psumsq);
    finalize_stats_kernel<<<dim3(BB), dim3(128), 0, stream>>>(psum, psumsq, mask, meanp, istdp);
    write_out_kernel<<<dim3(1024), dim3(256), 0, stream>>>(
        mask, dist, eidx, meanp, istdp, scale, shift, out);
}